// Round 1
// baseline (24420.244 us; speedup 1.0000x reference)
//
#include <hip/hip_runtime.h>
#include <cstdint>
#include <cstddef>

#define H     1024
#define BATCH 16
#define SEQ   2000
#define NOUT  8
#define G     64       // workgroups (persistent), 16 rows each
#define RPW   16       // rows per WG
#define TPB   256
#define LPAD  1028     // padded LDS row (breaks bank conflicts, keeps 16B align)

// d_out offsets (in floats): n_all, h_all, r_all, u_all, z_all
#define N_OFF 0
#define H_OFF 32768000
#define R_OFF 65536000
#define U_OFF 98304000
#define Z_OFF 131072000

// ws layout (bytes)
#define FLAGS_OFF 0          // 64 flags, each padded to 32 uints (128B line)
#define SBUF_OFF  8192       // double-buffered s: 2 * 16*1024 floats
#define IREP_OFF  139264     // I repacked [t][b]: 2000*16 floats
#define ZPART_OFF 267264     // zpart [t][g][b]: 2000*64*16 floats

__global__ void init_kernel(const float* __restrict__ I, float* __restrict__ Irep,
                            unsigned int* __restrict__ flags) {
  int tid = blockIdx.x * blockDim.x + threadIdx.x;
  if (tid < SEQ * BATCH) {
    int t = tid >> 4, b = tid & 15;
    Irep[tid] = I[b * SEQ + t];            // I is [B, SEQ, 1]
  }
  if (tid < G) flags[tid * 32] = 0u;
}

__global__ __launch_bounds__(TPB, 1) void rnn_persist(
    const float* __restrict__ h0, const float* __restrict__ r0, const float* __restrict__ u0,
    const float* __restrict__ Wih, const float* __restrict__ offih,
    const float* __restrict__ Whh, const float* __restrict__ Whz,
    const float* __restrict__ prel, const float* __restrict__ Whhm, const float* __restrict__ Whzm,
    const float* __restrict__ Irep, float* __restrict__ sbuf, unsigned int* flags,
    float* __restrict__ zpart, float* __restrict__ dout)
{
  __shared__ float wL[RPW][LPAD];    // masked W_hh rows for this WG
  __shared__ float sL[BATCH][LPAD];  // staged s_t, [b][j]
  __shared__ float zsc[BATCH];

  const int g = blockIdx.x, tid = threadIdx.x;
  const int r = tid & 15, b = tid >> 4;   // lane = b*16 + r
  const int row = g * RPW + r;

  // ---- one-time: stage masked recurrent weights into LDS ----
  {
    const float4* wsrc = (const float4*)(Whh + (size_t)g * RPW * H);
    const float4* msrc = (const float4*)(Whhm + (size_t)g * RPW * H);
    for (int k = tid; k < RPW * H / 4; k += TPB) {
      float4 w = wsrc[k], m = msrc[k];
      int rr = k >> 8, c = (k & 255) << 2;
      wL[rr][c]     = w.x * m.x;
      wL[rr][c + 1] = w.y * m.y;
      wL[rr][c + 2] = w.z * m.z;
      wL[rr][c + 3] = w.w * m.w;
    }
  }

  // ---- per-lane persistent state (registers for all 2000 steps) ----
  const int sidx = b * H + row;
  float h  = h0[sidx], rr_ = r0[sidx], u = u0[sidx];
  float p  = prel[row], psyn = 1.0f / p;
  float wih = Wih[row], oih = offih[row];
  const int o = row >> 7;
  float wz = Whz[o * H + row] * Whzm[o * H + row];
  float ht = 1.0f / (1.0f + expf(-8.0f * (h - 0.5f)));

  sbuf[sidx] = ht * rr_ * u * psyn;          // s_0 -> buffer 0
  __syncthreads();
  if (tid == 0) {
    __threadfence();                          // release: flush s_0 to LLC
    __hip_atomic_store(&flags[g * 32], 1u, __ATOMIC_RELAXED, __HIP_MEMORY_SCOPE_AGENT);
  }

  float* outh = dout + H_OFF + (size_t)b * (SEQ * H) + row;
  float* outr = dout + R_OFF + (size_t)b * (SEQ * H) + row;
  float* outu = dout + U_OFF + (size_t)b * (SEQ * H) + row;
  unsigned int* myflag = flags + ((tid & 63) << 5);   // each wave checks all 64 flags

  for (int t = 0; t < SEQ; ++t) {
    // ---- wait: all WGs published s_t ----
    const unsigned int tgt = (unsigned int)(t + 1);
    for (int it = 0; it < (1 << 14); ++it) {  // bounded spin (hang safety)
      if (__hip_atomic_load(myflag, __ATOMIC_RELAXED, __HIP_MEMORY_SCOPE_AGENT) >= tgt) break;
    }
    __threadfence();                          // acquire: invalidate L1/L2 for fresh sbuf

    float It = Irep[t * BATCH + b];

    // ---- stage s_t (64KB) into LDS ----
    const float* sb = sbuf + (t & 1) * (BATCH * H);
    #pragma unroll
    for (int k = 0; k < 16; ++k) {
      int d4 = k * TPB + tid;                 // float4 index over 4096
      int bb = d4 >> 8, j = (d4 & 255) << 2;
      float4 v = *(const float4*)(sb + bb * H + j);
      *(float4*)&sL[bb][j] = v;
    }
    __syncthreads();

    // ---- rec[row][b] = sum_j wL[r][j] * sL[b][j] (4 indep accumulators) ----
    float a0 = 0.f, a1 = 0.f, a2 = 0.f, a3 = 0.f;
    const float4* wrow = (const float4*)&wL[r][0];
    const float4* srow = (const float4*)&sL[b][0];
    #pragma unroll 8
    for (int c = 0; c < H / 4; ++c) {
      float4 w4 = wrow[c], s4 = srow[c];
      a0 = fmaf(w4.x, s4.x, a0);
      a1 = fmaf(w4.y, s4.y, a1);
      a2 = fmaf(w4.z, s4.z, a2);
      a3 = fmaf(w4.w, s4.w, a3);
    }
    float rec = (a0 + a1) + (a2 + a3);

    // ---- state update (matches reference op order; n == 0 always) ----
    float ext = It * wih + oih;
    float hn  = h + ((-h + rec + ext) / 0.01f) * 0.001f;
    float htn = 1.0f / (1.0f + expf(-8.0f * (hn - 0.5f)));
    float rn  = rr_ + ((1.0f - rr_) / 0.2f - 50.0f * u * rr_ * ht) * 0.001f;
    float un  = u + ((p - u) / 1.5f + 50.0f * p * (1.0f - u) * ht) * 0.001f;

    outh[t * H] = hn; outr[t * H] = rn; outu[t * H] = un;

    // ---- z partial: sum over this WG's 16 rows (lane bits 0-3) ----
    float zl = htn * wz;
    zl += __shfl_xor(zl, 1); zl += __shfl_xor(zl, 2);
    zl += __shfl_xor(zl, 4); zl += __shfl_xor(zl, 8);
    if (r == 0) zsc[b] = zl;

    // ---- publish s_{t+1} ----
    float sn = htn * rn * un * psyn;
    sbuf[((t + 1) & 1) * (BATCH * H) + sidx] = sn;

    h = hn; ht = htn; rr_ = rn; u = un;

    __syncthreads();   // zsc ready; all waves' global s-stores drained (vmcnt0 at barrier)
    if (tid < BATCH) zpart[((size_t)t * G + g) * BATCH + tid] = zsc[tid];
    if (tid == 0) {
      __threadfence();  // release: flush s_{t+1} (all waves' stores are in L2 by now)
      __hip_atomic_store(&flags[g * 32], (unsigned int)(t + 2), __ATOMIC_RELAXED, __HIP_MEMORY_SCOPE_AGENT);
    }
  }
}

__global__ void zred_kernel(const float* __restrict__ zpart, const float* __restrict__ offhz,
                            float* __restrict__ zout) {
  int tid = blockIdx.x * blockDim.x + threadIdx.x;
  if (tid >= BATCH * SEQ * NOUT) return;
  int b = tid / (SEQ * NOUT);
  int rem = tid - b * (SEQ * NOUT);
  int t = rem >> 3, o = rem & 7;
  float acc = offhz[o];
  #pragma unroll
  for (int k = 0; k < G / NOUT; ++k)
    acc += zpart[((size_t)t * G + o * (G / NOUT) + k) * BATCH + b];
  zout[tid] = acc;   // z_all[b][t][o]
}

extern "C" void kernel_launch(void* const* d_in, const int* in_sizes, int n_in,
                              void* d_out, int out_size, void* d_ws, size_t ws_size,
                              hipStream_t stream) {
  const float* I     = (const float*)d_in[0];
  const float* h0    = (const float*)d_in[1];
  const float* r0    = (const float*)d_in[2];
  const float* u0    = (const float*)d_in[3];
  const float* Wih   = (const float*)d_in[4];
  const float* offih = (const float*)d_in[5];
  const float* Whh   = (const float*)d_in[6];
  const float* Whz   = (const float*)d_in[7];
  const float* offhz = (const float*)d_in[8];
  const float* prel  = (const float*)d_in[9];
  const float* Whhm  = (const float*)d_in[10];
  const float* Whzm  = (const float*)d_in[11];
  float* out = (float*)d_out;

  unsigned int* flags = (unsigned int*)((char*)d_ws + FLAGS_OFF);
  float* sbuf  = (float*)((char*)d_ws + SBUF_OFF);
  float* Irep  = (float*)((char*)d_ws + IREP_OFF);
  float* zpart = (float*)((char*)d_ws + ZPART_OFF);

  // n_all is identically zero
  hipMemsetAsync(d_out, 0, (size_t)H_OFF * sizeof(float), stream);
  init_kernel<<<(SEQ * BATCH + 255) / 256, 256, 0, stream>>>(I, Irep, flags);
  rnn_persist<<<G, TPB, 0, stream>>>(h0, r0, u0, Wih, offih, Whh, Whz, prel, Whhm, Whzm,
                                     Irep, sbuf, flags, zpart, out);
  zred_kernel<<<(BATCH * SEQ * NOUT + 255) / 256, 256, 0, stream>>>(zpart, offhz, out + Z_OFF);
}